// Round 18
// baseline (134.347 us; speedup 1.0000x reference)
//
#include <hip/hip_runtime.h>
#include <hip/hip_bf16.h>

// x: (2,32,32,480) fp32; qkv_w: (96,32,3,3); qkv_b: (96,); out_w: (32,32,3,3)
// D_MODEL=32, N_HEADS=8, dh=4, QUERY_SHAPE=24, MEM_FLANGE=8
// H=32, W=480, nb=20, wlen=40; per (b,h,blk): 768 queries x 1280 keys.

#define HW 15360      // 32*480, one channel plane
#define VSTRIDE 1300  // halves; 650 dwords = 10 mod 32 -> max 2-way bank alias

typedef _Float16 half4 __attribute__((ext_vector_type(4)));
typedef float floatx4 __attribute__((ext_vector_type(4)));
using fh2 = decltype(__builtin_amdgcn_cvt_pkrtz(0.f, 0.f));

// ---------------------------------------------------------------------------
// Repack BOTH weight tensors [Cout][32][3][3] -> packed-f16 pairs over ci:
// wtu[(ci2*9 + tap)*Cout + co] = pack_f16(w[co][2ci2][tap], w[co][2ci2+1][tap])
// ---------------------------------------------------------------------------
__global__ __launch_bounds__(256) void repack_both(
    const float* __restrict__ w1, unsigned* __restrict__ wt1,
    const float* __restrict__ w2, unsigned* __restrict__ wt2) {
    int i = blockIdx.x * 256 + threadIdx.x;
    if (i < 96 * 144) {
        int co = i / 144, r = i - co * 144;
        int ci2 = r / 9, tap = r - ci2 * 9;
        float a = w1[co * 288 + (2 * ci2) * 9 + tap];
        float b = w1[co * 288 + (2 * ci2) * 9 + 9 + tap];
        fh2 p = __builtin_amdgcn_cvt_pkrtz(a, b);
        wt1[(ci2 * 9 + tap) * 96 + co] = __builtin_bit_cast(unsigned, p);
    } else if (i < 96 * 144 + 32 * 144) {
        int i2 = i - 96 * 144;
        int co = i2 / 144, r = i2 - co * 144;
        int ci2 = r / 9, tap = r - ci2 * 9;
        float a = w2[co * 288 + (2 * ci2) * 9 + tap];
        float b = w2[co * 288 + (2 * ci2) * 9 + 9 + tap];
        fh2 p = __builtin_amdgcn_cvt_pkrtz(a, b);
        wt2[(ci2 * 9 + tap) * 32 + co] = __builtin_bit_cast(unsigned, p);
    }
}

// ---------------------------------------------------------------------------
// LDS-staged 3x3 conv, pad 1, NCHW, Cin=32, f32 input. WG = 512 threads =
// one (b, y-row, co-tile); threads 0..479 compute one pixel x CO_TILE co.
// Input staged in 4 chunks of 8 ci as ci-pair-interleaved packed-f16 u32
// ([4 ci2][3 rows][482 cols], 23.1 KB): one ds_read_b32 = one dot2 operand.
// Halo zero-filled at staging (no masks in compute). Round-17 lesson: conv
// was VMEM-issue bound (288 strided loads/thread); staging cuts it to ~90
// coalesced.
// ---------------------------------------------------------------------------
template<int CO_TILE, typename TOUT>
__global__ __launch_bounds__(512) void conv3x3_lds(
    const float* __restrict__ in, const unsigned* __restrict__ wt,
    const float* __restrict__ bias, TOUT* __restrict__ out, int Cout)
{
    __shared__ unsigned tile[4 * 3 * 482];   // 5784 u32 = 23.1 KB

    int nct = Cout / CO_TILE;
    int bc  = blockIdx.y;            // b*nct + ct
    int ct  = bc % nct;
    int b   = bc / nct;
    int co0 = ct * CO_TILE;
    int y   = blockIdx.x;            // 0..31
    int tid = threadIdx.x;
    int w   = tid;                   // pixel col; active if < 480

    float acc[CO_TILE];
#pragma unroll
    for (int i = 0; i < CO_TILE; ++i) acc[i] = bias ? bias[co0 + i] : 0.f;

    const float* ibase = in + (size_t)b * 32 * HW;

    for (int chunk = 0; chunk < 4; ++chunk) {
        int ci0 = chunk * 8;
        // ---- stage 8 ci (4 pairs) x 3 rows x 482 cols ----
        for (int e = tid; e < 5784; e += 512) {
            int ci2l = e / 1446;
            int rem  = e - ci2l * 1446;
            int r    = rem / 482;
            int cc   = rem - r * 482;
            int yg   = y + r - 1;
            int wgc  = cc - 1;
            unsigned val = 0;
            if ((unsigned)yg < 32u && (unsigned)wgc < 480u) {
                const float* p = ibase + (size_t)(ci0 + 2 * ci2l) * HW + yg * 480 + wgc;
                val = __builtin_bit_cast(unsigned,
                        __builtin_amdgcn_cvt_pkrtz(p[0], p[HW]));
            }
            tile[e] = val;
        }
        __syncthreads();

        // ---- compute 4 ci-pairs from LDS ----
        if (w < 480) {
#pragma unroll
            for (int ci2l = 0; ci2l < 4; ++ci2l) {
                const unsigned* trow = &tile[ci2l * 1446];
                fh2 v2[9];
#pragma unroll
                for (int r = 0; r < 3; ++r)
#pragma unroll
                    for (int c = 0; c < 3; ++c)
                        v2[r * 3 + c] = __builtin_bit_cast(fh2,
                            trow[r * 482 + w + c]);

                int ci2g = chunk * 4 + ci2l;
                const unsigned* wrow = wt + (ci2g * 9) * Cout + co0;
#pragma unroll
                for (int k = 0; k < 9; ++k) {
                    const uint4* w4p = (const uint4*)(wrow + k * Cout);
#pragma unroll
                    for (int c = 0; c < CO_TILE / 4; ++c) {
                        uint4 ww = w4p[c];
                        acc[c * 4 + 0] = __builtin_amdgcn_fdot2(
                            v2[k], __builtin_bit_cast(fh2, ww.x), acc[c * 4 + 0], false);
                        acc[c * 4 + 1] = __builtin_amdgcn_fdot2(
                            v2[k], __builtin_bit_cast(fh2, ww.y), acc[c * 4 + 1], false);
                        acc[c * 4 + 2] = __builtin_amdgcn_fdot2(
                            v2[k], __builtin_bit_cast(fh2, ww.z), acc[c * 4 + 2], false);
                        acc[c * 4 + 3] = __builtin_amdgcn_fdot2(
                            v2[k], __builtin_bit_cast(fh2, ww.w), acc[c * 4 + 3], false);
                    }
                }
            }
        }
        __syncthreads();
    }

    if (w < 480) {
        size_t obase = (size_t)(b * Cout + co0) * HW + y * 480 + w;
#pragma unroll
        for (int i = 0; i < CO_TILE; ++i) out[obase + (size_t)i * HW] = (TOUT)acc[i];
    }
}

// ---------------------------------------------------------------------------
// MFMA flash attention (rounds 13/16/17 known-good, 52.7 us; f32 output).
// Grid: 1280 WGs = (b,h,blk) x 4 query-groups, XCD-swizzled. 256 threads
// (4 waves), each wave 3 q-tiles of 16 queries. S' = K·Q^T via
// mfma_16x16x16_f16 (swapped operands: C-frag of S' == A-frag of P), exp2
// in-register, P·[V|1|0] second MFMA; ones-row of V^T gives the denominator.
// Idle fragment lanes read a zeroed LDS slot with stride 0.
// ---------------------------------------------------------------------------
__global__ __launch_bounds__(256) void attn_mfma(
    const _Float16* __restrict__ qkv, float* __restrict__ att)
{
    __shared__ _Float16 Kl[1280 * 4];      // [j][d] key-major, 8B/key
    __shared__ _Float16 Vl[5 * VSTRIDE];   // [n][j] transposed; row 4 = ones
    __shared__ _Float16 Zl[8];             // zero slot for idle lanes

    int wg    = blockIdx.x;
    int orig  = (wg & 7) * 160 + (wg >> 3);   // XCD-contiguous remap (bijective)
    int qg    = orig & 3;
    int bhblk = orig >> 2;
    int blk = bhblk % 20;
    int h   = (bhblk / 20) % 8;
    int b   = bhblk / 160;
    int tid  = threadIdx.x;
    int lane = tid & 63;
    int wv   = tid >> 6;     // 0..3

    const _Float16* base = qkv + (size_t)(b * 96 + h * 12) * HW;
    const _Float16* kb = base + 4 * HW;
    const _Float16* vb = base + 8 * HW;

    const _Float16 h0 = (_Float16)0.f;
    if (tid < 2) *(half4*)&Zl[tid * 4] = half4{ h0, h0, h0, h0 };

    // stage K (key-major) and V^T (+ones row) into LDS
    for (int j = tid; j < 1280; j += 256) {
        int yy = j / 40, wc = j - yy * 40;
        int wpos = blk * 24 + wc - 8;
        _Float16 k0 = h0, k1 = h0, k2 = h0, k3 = h0;
        _Float16 v0 = h0, v1 = h0, v2 = h0, v3 = h0;
        if ((unsigned)wpos < 480u) {
            int o = yy * 480 + wpos;
            k0 = kb[o]; k1 = kb[o + HW]; k2 = kb[o + 2 * HW]; k3 = kb[o + 3 * HW];
            v0 = vb[o]; v1 = vb[o + HW]; v2 = vb[o + 2 * HW]; v3 = vb[o + 3 * HW];
        }
        *(half4*)&Kl[j * 4] = half4{ k0, k1, k2, k3 };
        Vl[j]               = v0;
        Vl[VSTRIDE + j]     = v1;
        Vl[2 * VSTRIDE + j] = v2;
        Vl[3 * VSTRIDE + j] = v3;
        Vl[4 * VSTRIDE + j] = (_Float16)1.0f;
    }

    // Q B-frags: lane<16 holds query (tile_base+lane)'s 4 dims (pre-scaled)
    const float QS = 0.5f * 1.44269504f;   // dh^-0.5 * log2(e)
    half4 qf[3];
#pragma unroll
    for (int t = 0; t < 3; ++t) {
        half4 qq = { h0, h0, h0, h0 };
        if (lane < 16) {
            int q = qg * 192 + (wv * 3 + t) * 16 + lane;
            int y = q / 24, qc = q - y * 24;
            int o = y * 480 + blk * 24 + qc;
            qq[0] = (_Float16)((float)base[o] * QS);
            qq[1] = (_Float16)((float)base[o + HW] * QS);
            qq[2] = (_Float16)((float)base[o + 2 * HW] * QS);
            qq[3] = (_Float16)((float)base[o + 3 * HW] * QS);
        }
        qf[t] = qq;
    }

    __syncthreads();

    const floatx4 fz = { 0.f, 0.f, 0.f, 0.f };
    floatx4 acc[3];
#pragma unroll
    for (int t = 0; t < 3; ++t) acc[t] = fz;

    int n = lane & 15;          // A-row (key) for ka; B-col (out dim) for vv
    int g = lane >> 4;

    // stride-0 zero-slot pointers for idle lanes (replaces per-iter cndmask)
    const _Float16* kap = (lane < 16) ? &Kl[n * 4] : Zl;
    int kstep = (lane < 16) ? 64 : 0;              // 16 keys * 4 halves
    const _Float16* vap = (n <= 4) ? &Vl[n * VSTRIDE + g * 4] : Zl;
    int vstep = (n <= 4) ? 16 : 0;                 // 16 halves

    for (int kt = 0; kt < 80; ++kt) {
        half4 ka = *(const half4*)kap; kap += kstep;
        half4 vv = *(const half4*)vap; vap += vstep;
#pragma unroll
        for (int t = 0; t < 3; ++t) {
            floatx4 s = __builtin_amdgcn_mfma_f32_16x16x16f16(ka, qf[t], fz, 0, 0, 0);
            auto lo = __builtin_amdgcn_cvt_pkrtz(__builtin_amdgcn_exp2f(s[0]),
                                                 __builtin_amdgcn_exp2f(s[1]));
            auto hi = __builtin_amdgcn_cvt_pkrtz(__builtin_amdgcn_exp2f(s[2]),
                                                 __builtin_amdgcn_exp2f(s[3]));
            half4 pa = { (_Float16)lo[0], (_Float16)lo[1],
                         (_Float16)hi[0], (_Float16)hi[1] };
            acc[t] = __builtin_amdgcn_mfma_f32_16x16x16f16(pa, vv, acc[t], 0, 0, 0);
        }
    }

    // epilogue: lane holds O[q = tile+g*4+r][n]; col 4 = softmax denominator
#pragma unroll
    for (int t = 0; t < 3; ++t) {
#pragma unroll
        for (int r = 0; r < 4; ++r) {
            float ls = __shfl(acc[t][r], (lane & 48) + 4);
            if (n < 4) {
                float val = acc[t][r] * __builtin_amdgcn_rcpf(ls);
                int q = qg * 192 + (wv * 3 + t) * 16 + g * 4 + r;
                int y = q / 24, qc = q - y * 24;
                att[((size_t)(b * 32 + h * 4 + n) * 32 + y) * 480 + blk * 24 + qc] = val;
            }
        }
    }
}

extern "C" void kernel_launch(void* const* d_in, const int* in_sizes, int n_in,
                              void* d_out, int out_size, void* d_ws, size_t ws_size,
                              hipStream_t stream) {
    const float* x     = (const float*)d_in[0];
    const float* qkv_w = (const float*)d_in[1];
    const float* qkv_b = (const float*)d_in[2];
    const float* out_w = (const float*)d_in[3];
    float* out = (float*)d_out;

    unsigned* wt1 = (unsigned*)d_ws;                     // 96*144 = 13,824 u32
    unsigned* wt2 = wt1 + 96 * 144;                      // 32*144 = 4,608 u32
    _Float16* qkv16 = (_Float16*)(wt2 + 32 * 144);       // 2*96*HW halves (5.9 MB)
    float* attf = (float*)(qkv16 + (size_t)2 * 96 * HW); // 2*32*HW f32 (3.9 MB)

    // fused weight repack (packed-f16 ci-pairs)
    repack_both<<<(96 * 144 + 32 * 144 + 255) / 256, 256, 0, stream>>>(
        qkv_w, wt1, out_w, wt2);

    // conv1: x (f32) -> qkv16 (f16); LDS-staged, dot2; 1 px x 8 co, 768 WGs
    conv3x3_lds<8, _Float16>
        <<<dim3(32, 2 * 12), 512, 0, stream>>>(x, wt1, qkv_b, qkv16, 96);

    // attention (MFMA flash, XCD-swizzled): qkv16 -> attf (f32)
    attn_mfma<<<1280, 256, 0, stream>>>(qkv16, attf);

    // conv2: attf (f32) -> out (f32); LDS-staged, dot2; 1 px x 4 co, 512 WGs
    conv3x3_lds<4, float>
        <<<dim3(32, 2 * 8), 512, 0, stream>>>(attf, wt2, nullptr, out, 32);
}

// Round 19
// 78.426 us; speedup vs baseline: 1.7130x; 1.7130x over previous
//
#include <hip/hip_runtime.h>
#include <hip/hip_bf16.h>

// x: (2,32,32,480) fp32; qkv_w: (96,32,3,3); qkv_b: (96,); out_w: (32,32,3,3)
// D_MODEL=32, N_HEADS=8, dh=4, QUERY_SHAPE=24, MEM_FLANGE=8
// H=32, W=480, nb=20, wlen=40; per (b,h,blk): 768 queries x 1280 keys.

#define HW 15360      // 32*480, one channel plane
#define VSTRIDE 1300  // halves; 650 dwords = 10 mod 32 -> max 2-way bank alias

typedef _Float16 half4 __attribute__((ext_vector_type(4)));
typedef float floatx4 __attribute__((ext_vector_type(4)));
using fh2 = decltype(__builtin_amdgcn_cvt_pkrtz(0.f, 0.f));

// ---------------------------------------------------------------------------
// GEMM-layout weight repack. k-order: k = tap*32 + ci (tap in 0..8, ci 0..31).
// wA[(m*18+kt)*64 + lane] = f16{W[co][k0..k0+3]} with co = m*16 + (lane&15),
// k0 = kt*16 + (lane>>4)*4  — exactly the mfma_16x16x16_f16 A-fragment.
// ---------------------------------------------------------------------------
__global__ __launch_bounds__(256) void repack_gemm(
    const float* __restrict__ w1, uint2* __restrict__ wA1,
    const float* __restrict__ w2, uint2* __restrict__ wA2) {
    int i = blockIdx.x * 256 + threadIdx.x;
    const float* src; uint2* dst; int rel;
    if (i < 6 * 18 * 64)            { src = w1; dst = wA1; rel = i; }
    else if (i < (6 + 2) * 18 * 64) { src = w2; dst = wA2; rel = i - 6 * 18 * 64; }
    else return;
    int lane = rel & 63;
    int mk   = rel >> 6;
    int kt   = mk % 18;
    int m    = mk / 18;
    int co   = m * 16 + (lane & 15);
    int k0   = kt * 16 + (lane >> 4) * 4;
    float v[4];
#pragma unroll
    for (int j = 0; j < 4; ++j) {
        int k = k0 + j, tap = k >> 5, ci = k & 31;
        v[j] = src[co * 288 + ci * 9 + tap];
    }
    unsigned lo = __builtin_bit_cast(unsigned, __builtin_amdgcn_cvt_pkrtz(v[0], v[1]));
    unsigned hi = __builtin_bit_cast(unsigned, __builtin_amdgcn_cvt_pkrtz(v[2], v[3]));
    dst[mk * 64 + lane] = make_uint2(lo, hi);
}

// ---------------------------------------------------------------------------
// conv1 as MFMA GEMM: qkv[co][px] = sum_k W[co][k] * im2col[k][px].
// WG = 256 thr (4 waves) = (b, y-quad, x-block16, co-half). Wave w owns row
// y0+w, 16 pixels, 3 co-tiles. Input staged once to LDS f16 [6][18][36-pad];
// 18 B-frags (one ds_read_b64 each) hoisted to regs; 18x3 MFMA.
// ---------------------------------------------------------------------------
__global__ __launch_bounds__(256) void conv1_gemm(
    const float* __restrict__ x, const uint2* __restrict__ wA,
    const float* __restrict__ bias, _Float16* __restrict__ qkv)
{
    __shared__ _Float16 S[6 * 18 * 36];   // 7776 B

    int xb  = blockIdx.x;            // 0..29
    int byq = blockIdx.y;            // b*8 + yq
    int mb  = blockIdx.z;            // co-half: m_base = mb*3
    int yq = byq & 7, b = byq >> 3;
    int y0 = yq * 4, x0 = xb * 16;
    int tid = threadIdx.x, lane = tid & 63, wv = tid >> 6;

    // stage [row 0..5][col 0..17][ci 0..31]; halo zero-filled
    const float* xb_ = x + (size_t)b * 32 * HW;
    for (int e = tid; e < 3456; e += 256) {
        int col = e % 18; int t2 = e / 18; int row = t2 % 6; int ci = t2 / 6;
        int yg = y0 + row - 1, xg = x0 + col - 1;
        _Float16 v = (_Float16)0.f;
        if ((unsigned)yg < 32u && (unsigned)xg < 480u)
            v = (_Float16)xb_[ci * HW + yg * 480 + xg];
        S[(row * 18 + col) * 36 + ci] = v;
    }
    __syncthreads();

    int cb = lane & 15, kg = lane >> 4;

    // hoist 18 B-frags for this wave's row
    half4 Bf[18];
#pragma unroll
    for (int kt = 0; kt < 18; ++kt) {
        int tap = kt >> 1;
        int dy = tap / 3, dx = tap % 3;            // 0..2 (staged offsets)
        int ci0 = (kt & 1) * 16 + kg * 4;
        Bf[kt] = *(const half4*)&S[((wv + dy) * 18 + cb + dx) * 36 + ci0];
    }

    floatx4 acc[3];
#pragma unroll
    for (int m = 0; m < 3; ++m) {
        const float4 bz = *(const float4*)&bias[(mb * 3 + m) * 16 + kg * 4];
        acc[m] = floatx4{ bz.x, bz.y, bz.z, bz.w };
    }

    for (int kt = 0; kt < 18; ++kt) {
        half4 bb = Bf[kt];
#pragma unroll
        for (int m = 0; m < 3; ++m) {
            uint2 aw = wA[((mb * 3 + m) * 18 + kt) * 64 + lane];
            acc[m] = __builtin_amdgcn_mfma_f32_16x16x16f16(
                __builtin_bit_cast(half4, aw), bb, acc[m], 0, 0, 0);
        }
    }

    // C: co = M-tile*16 + kg*4 + r, px-col = cb
    size_t obase = (size_t)b * 96 * HW + (y0 + wv) * 480 + x0 + cb;
#pragma unroll
    for (int m = 0; m < 3; ++m)
#pragma unroll
        for (int r = 0; r < 4; ++r)
            qkv[obase + (size_t)((mb * 3 + m) * 16 + kg * 4 + r) * HW] =
                (_Float16)acc[m][r];
}

// ---------------------------------------------------------------------------
// conv2 as MFMA GEMM. Input att is PIXEL-MAJOR f16 [b][px][32ch] (written by
// attn), so B-frags (4 consecutive ci at one pixel) load DIRECTLY from global
// as 8B — no LDS, no cvt. OOB halo -> zero via cndmask. 2 co-tiles.
// ---------------------------------------------------------------------------
__global__ __launch_bounds__(256) void conv2_gemm(
    const _Float16* __restrict__ att, const uint2* __restrict__ wA,
    float* __restrict__ out)
{
    int xb  = blockIdx.x;            // 0..29
    int byq = blockIdx.y;            // b*8 + yq
    int yq = byq & 7, b = byq >> 3;
    int y0 = yq * 4, x0 = xb * 16;
    int tid = threadIdx.x, lane = tid & 63, wv = tid >> 6;
    int cb = lane & 15, kg = lane >> 4;
    int yrow = y0 + wv;

    const _Float16* ab = att + (size_t)b * 15360 * 32;
    const half4 hz = { (_Float16)0.f, (_Float16)0.f, (_Float16)0.f, (_Float16)0.f };

    half4 Bf[18];
#pragma unroll
    for (int kt = 0; kt < 18; ++kt) {
        int tap = kt >> 1;
        int dy = tap / 3 - 1, dx = tap % 3 - 1;
        int ci0 = (kt & 1) * 16 + kg * 4;
        int yg = yrow + dy, xg = x0 + cb + dx;
        bool ok = ((unsigned)yg < 32u) & ((unsigned)xg < 480u);
        int yc = ok ? yg : 0, xc = ok ? xg : 0;
        half4 v = *(const half4*)&ab[((size_t)yc * 480 + xc) * 32 + ci0];
        Bf[kt] = ok ? v : hz;
    }

    floatx4 acc[2];
    acc[0] = floatx4{0.f, 0.f, 0.f, 0.f};
    acc[1] = floatx4{0.f, 0.f, 0.f, 0.f};

    for (int kt = 0; kt < 18; ++kt) {
        half4 bb = Bf[kt];
#pragma unroll
        for (int m = 0; m < 2; ++m) {
            uint2 aw = wA[(m * 18 + kt) * 64 + lane];
            acc[m] = __builtin_amdgcn_mfma_f32_16x16x16f16(
                __builtin_bit_cast(half4, aw), bb, acc[m], 0, 0, 0);
        }
    }

    size_t obase = (size_t)b * 32 * HW + yrow * 480 + x0 + cb;
#pragma unroll
    for (int m = 0; m < 2; ++m)
#pragma unroll
        for (int r = 0; r < 4; ++r)
            out[obase + (size_t)(m * 16 + kg * 4 + r) * HW] = acc[m][r];
}

// ---------------------------------------------------------------------------
// MFMA flash attention (rounds 13/16/17/18 known-good, 52.7 us). ONLY change:
// output store is now pixel-major f16 att[b][px][32ch] for conv2's direct
// global B-frag loads. Grid: 1280 WGs XCD-swizzled, 256 thr (4 waves),
// 3 q-tiles/wave. S' = K·Q^T (swapped operands), exp2 in-register, P·[V|1|0];
// ones-row of V^T gives the denominator. Idle lanes read zeroed LDS slot.
// ---------------------------------------------------------------------------
__global__ __launch_bounds__(256) void attn_mfma(
    const _Float16* __restrict__ qkv, _Float16* __restrict__ att)
{
    __shared__ _Float16 Kl[1280 * 4];      // [j][d] key-major, 8B/key
    __shared__ _Float16 Vl[5 * VSTRIDE];   // [n][j] transposed; row 4 = ones
    __shared__ _Float16 Zl[8];             // zero slot for idle lanes

    int wg    = blockIdx.x;
    int orig  = (wg & 7) * 160 + (wg >> 3);   // XCD-contiguous remap (bijective)
    int qg    = orig & 3;
    int bhblk = orig >> 2;
    int blk = bhblk % 20;
    int h   = (bhblk / 20) % 8;
    int b   = bhblk / 160;
    int tid  = threadIdx.x;
    int lane = tid & 63;
    int wv   = tid >> 6;     // 0..3

    const _Float16* base = qkv + (size_t)(b * 96 + h * 12) * HW;
    const _Float16* kb = base + 4 * HW;
    const _Float16* vb = base + 8 * HW;

    const _Float16 h0 = (_Float16)0.f;
    if (tid < 2) *(half4*)&Zl[tid * 4] = half4{ h0, h0, h0, h0 };

    // stage K (key-major) and V^T (+ones row) into LDS
    for (int j = tid; j < 1280; j += 256) {
        int yy = j / 40, wc = j - yy * 40;
        int wpos = blk * 24 + wc - 8;
        _Float16 k0 = h0, k1 = h0, k2 = h0, k3 = h0;
        _Float16 v0 = h0, v1 = h0, v2 = h0, v3 = h0;
        if ((unsigned)wpos < 480u) {
            int o = yy * 480 + wpos;
            k0 = kb[o]; k1 = kb[o + HW]; k2 = kb[o + 2 * HW]; k3 = kb[o + 3 * HW];
            v0 = vb[o]; v1 = vb[o + HW]; v2 = vb[o + 2 * HW]; v3 = vb[o + 3 * HW];
        }
        *(half4*)&Kl[j * 4] = half4{ k0, k1, k2, k3 };
        Vl[j]               = v0;
        Vl[VSTRIDE + j]     = v1;
        Vl[2 * VSTRIDE + j] = v2;
        Vl[3 * VSTRIDE + j] = v3;
        Vl[4 * VSTRIDE + j] = (_Float16)1.0f;
    }

    // Q B-frags: lane<16 holds query (tile_base+lane)'s 4 dims (pre-scaled)
    const float QS = 0.5f * 1.44269504f;   // dh^-0.5 * log2(e)
    half4 qf[3];
#pragma unroll
    for (int t = 0; t < 3; ++t) {
        half4 qq = { h0, h0, h0, h0 };
        if (lane < 16) {
            int q = qg * 192 + (wv * 3 + t) * 16 + lane;
            int y = q / 24, qc = q - y * 24;
            int o = y * 480 + blk * 24 + qc;
            qq[0] = (_Float16)((float)base[o] * QS);
            qq[1] = (_Float16)((float)base[o + HW] * QS);
            qq[2] = (_Float16)((float)base[o + 2 * HW] * QS);
            qq[3] = (_Float16)((float)base[o + 3 * HW] * QS);
        }
        qf[t] = qq;
    }

    __syncthreads();

    const floatx4 fz = { 0.f, 0.f, 0.f, 0.f };
    floatx4 acc[3];
#pragma unroll
    for (int t = 0; t < 3; ++t) acc[t] = fz;

    int n = lane & 15;          // A-row (key) for ka; B-col (out dim) for vv
    int g = lane >> 4;

    // stride-0 zero-slot pointers for idle lanes (replaces per-iter cndmask)
    const _Float16* kap = (lane < 16) ? &Kl[n * 4] : Zl;
    int kstep = (lane < 16) ? 64 : 0;              // 16 keys * 4 halves
    const _Float16* vap = (n <= 4) ? &Vl[n * VSTRIDE + g * 4] : Zl;
    int vstep = (n <= 4) ? 16 : 0;                 // 16 halves

    for (int kt = 0; kt < 80; ++kt) {
        half4 ka = *(const half4*)kap; kap += kstep;
        half4 vv = *(const half4*)vap; vap += vstep;
#pragma unroll
        for (int t = 0; t < 3; ++t) {
            floatx4 s = __builtin_amdgcn_mfma_f32_16x16x16f16(ka, qf[t], fz, 0, 0, 0);
            auto lo = __builtin_amdgcn_cvt_pkrtz(__builtin_amdgcn_exp2f(s[0]),
                                                 __builtin_amdgcn_exp2f(s[1]));
            auto hi = __builtin_amdgcn_cvt_pkrtz(__builtin_amdgcn_exp2f(s[2]),
                                                 __builtin_amdgcn_exp2f(s[3]));
            half4 pa = { (_Float16)lo[0], (_Float16)lo[1],
                         (_Float16)hi[0], (_Float16)hi[1] };
            acc[t] = __builtin_amdgcn_mfma_f32_16x16x16f16(pa, vv, acc[t], 0, 0, 0);
        }
    }

    // epilogue: lane holds O[q = tile+g*4+r][n]; col 4 = softmax denominator.
    // Store PIXEL-MAJOR: att[(b*15360 + y*480 + x)*32 + ch]
#pragma unroll
    for (int t = 0; t < 3; ++t) {
#pragma unroll
        for (int r = 0; r < 4; ++r) {
            float ls = __shfl(acc[t][r], (lane & 48) + 4);
            if (n < 4) {
                float val = acc[t][r] * __builtin_amdgcn_rcpf(ls);
                int q = qg * 192 + (wv * 3 + t) * 16 + g * 4 + r;
                int y = q / 24, qc = q - y * 24;
                att[((size_t)b * 15360 + y * 480 + blk * 24 + qc) * 32 + h * 4 + n] =
                    (_Float16)val;
            }
        }
    }
}

extern "C" void kernel_launch(void* const* d_in, const int* in_sizes, int n_in,
                              void* d_out, int out_size, void* d_ws, size_t ws_size,
                              hipStream_t stream) {
    const float* x     = (const float*)d_in[0];
    const float* qkv_w = (const float*)d_in[1];
    const float* qkv_b = (const float*)d_in[2];
    const float* out_w = (const float*)d_in[3];
    float* out = (float*)d_out;

    uint2* wA1 = (uint2*)d_ws;                           // 6*18*64 = 6912 uint2
    uint2* wA2 = wA1 + 6 * 18 * 64;                      // 2*18*64 = 2304 uint2
    _Float16* qkv16 = (_Float16*)(wA2 + 2 * 18 * 64);    // 2*96*HW halves (5.9 MB)
    _Float16* att16 = qkv16 + (size_t)2 * 96 * HW;       // 2*15360*32 halves (2 MB)

    // GEMM-fragment weight repack
    repack_gemm<<<(8 * 18 * 64 + 255) / 256, 256, 0, stream>>>(
        qkv_w, wA1, out_w, wA2);

    // conv1 (MFMA GEMM): x (f32) -> qkv16 (f16, channel-major); 960 WGs
    conv1_gemm<<<dim3(30, 16, 2), 256, 0, stream>>>(x, wA1, qkv_b, qkv16);

    // attention (MFMA flash, XCD-swizzled): qkv16 -> att16 (pixel-major f16)
    attn_mfma<<<1280, 256, 0, stream>>>(qkv16, att16);

    // conv2 (MFMA GEMM, direct-global B): att16 -> out (f32); 480 WGs
    conv2_gemm<<<dim3(30, 16), 256, 0, stream>>>(att16, wA2, out);
}